// Round 1
// baseline (144.116 us; speedup 1.0000x reference)
//
#include <hip/hip_runtime.h>

// Problem constants (B=4, N=2048, DIM=1024, HEAD=16, HD=64)
#define B_    4
#define N_    2048
#define DIM_  1024
#define HEAD_ 16
#define HD_   64
#define M_    (B_*N_)    // 8192 rows
#define E_    (2*DIM_)   // 2048 projection outputs

typedef short          frag8 __attribute__((ext_vector_type(8)));  // 8 bf16 (4 VGPRs)
typedef float          facc4 __attribute__((ext_vector_type(4)));  // MFMA accum
typedef unsigned short ush4  __attribute__((ext_vector_type(4)));

#define AS1 __attribute__((address_space(1)))
#define AS3 __attribute__((address_space(3)))

__device__ __forceinline__ void gld_lds16(const void* g, void* l) {
    // async global->LDS, 16B per lane; LDS dest = wave-uniform base + lane*16
    __builtin_amdgcn_global_load_lds((AS1 void*)(void*)g, (AS3 void*)l, 16, 0, 0);
}

__device__ __forceinline__ unsigned short f2bf(float f) {
    return __builtin_bit_cast(unsigned short, (__bf16)f);
}

// ---------------- Kernel 1: LayerNorm -> bf16 ----------------
__global__ __launch_bounds__(256) void ln_kernel(const float* __restrict__ x,
                                                 const float* __restrict__ lw,
                                                 const float* __restrict__ lb,
                                                 unsigned short* __restrict__ xn) {
    const int row = blockIdx.x;          // 0..8191
    const int t   = threadIdx.x;         // 256 threads, 4 elems each
    const float4 v = ((const float4*)(x + (size_t)row * DIM_))[t];
    float s  = v.x + v.y + v.z + v.w;
    float sq = v.x*v.x + v.y*v.y + v.z*v.z + v.w*v.w;
#pragma unroll
    for (int off = 32; off > 0; off >>= 1) {
        s  += __shfl_xor(s,  off);
        sq += __shfl_xor(sq, off);
    }
    __shared__ float red[8];
    const int w = t >> 6;
    if ((t & 63) == 0) { red[w] = s; red[4 + w] = sq; }
    __syncthreads();
    s  = red[0] + red[1] + red[2] + red[3];
    sq = red[4] + red[5] + red[6] + red[7];
    const float mu   = s * (1.0f / DIM_);
    const float rstd = rsqrtf(sq * (1.0f / DIM_) - mu * mu + 1e-5f);
    const float4 wv4 = ((const float4*)lw)[t];
    const float4 bv4 = ((const float4*)lb)[t];
    ush4 o;
    o[0] = f2bf((v.x - mu) * rstd * wv4.x + bv4.x);
    o[1] = f2bf((v.y - mu) * rstd * wv4.y + bv4.y);
    o[2] = f2bf((v.z - mu) * rstd * wv4.z + bv4.z);
    o[3] = f2bf((v.w - mu) * rstd * wv4.w + bv4.w);
    *(ush4*)(xn + (size_t)row * DIM_ + t * 4) = o;
}

// ---------------- Kernel 1b: Wqk f32 -> bf16 ----------------
__global__ __launch_bounds__(256) void cvt_kernel(const float* __restrict__ in,
                                                  unsigned short* __restrict__ outp) {
    const int i = blockIdx.x * 256 + threadIdx.x;   // 524288 float4 groups
    const float4 v = ((const float4*)in)[i];
    ush4 o;
    o[0] = f2bf(v.x); o[1] = f2bf(v.y); o[2] = f2bf(v.z); o[3] = f2bf(v.w);
    ((ush4*)outp)[i] = o;
}

// ---------------- Kernel 2: qk = xn @ Wqk^T  (NT GEMM, bf16 MFMA) ----------------
// 128x128 tile, BK=64, 4 waves of 64x64. LDS rows are 128B; XOR-swizzle 16B
// segments (byte ^= (row&7)<<4) applied to the global SOURCE at staging and to
// the ds_read address (both-sides involution; linear global_load_lds dest).
__global__ __launch_bounds__(256) void gemm_qk(const unsigned short* __restrict__ xn,
                                               const unsigned short* __restrict__ wb,
                                               unsigned short* __restrict__ qo,
                                               unsigned short* __restrict__ ko) {
    __shared__ __attribute__((aligned(16))) unsigned short As[128 * 64];
    __shared__ __attribute__((aligned(16))) unsigned short Bs[128 * 64];
    const int t    = threadIdx.x;
    const int lane = t & 63;
    const int w    = t >> 6;
    const int wr   = w & 1, wc = w >> 1;        // 2x2 wave grid, 64x64 each
    const int lr   = lane & 15, lg = lane >> 4; // frag row-lane / k-group
    const int bm   = blockIdx.x & 63, bn = blockIdx.x >> 6;
    const int m0   = bm * 128, e0 = bn * 128;

    facc4 acc[4][4] = {};

    for (int k0 = 0; k0 < DIM_; k0 += 64) {
#pragma unroll
        for (int it = 0; it < 4; ++it) {
            const int seg = it * 256 + t;
            const int row = seg >> 3;
            const int ss  = (seg & 7) ^ (row & 7);         // pre-swizzled source
            unsigned short* dstA = (unsigned short*)As + (size_t)(it * 256 + (t & ~63)) * 8;
            unsigned short* dstB = (unsigned short*)Bs + (size_t)(it * 256 + (t & ~63)) * 8;
            gld_lds16(xn + (size_t)(m0 + row) * DIM_ + k0 + ss * 8, dstA);
            gld_lds16(wb + (size_t)(e0 + row) * DIM_ + k0 + ss * 8, dstB);
        }
        __syncthreads();

        frag8 af[4][2];
#pragma unroll
        for (int rt = 0; rt < 4; ++rt) {
            const int row = wr * 64 + rt * 16 + lr;
            const int sw  = (row & 7) << 4;
            af[rt][0] = *(const frag8*)((const char*)As + row * 128 + ((lg * 16) ^ sw));
            af[rt][1] = *(const frag8*)((const char*)As + row * 128 + ((64 + lg * 16) ^ sw));
        }
#pragma unroll
        for (int ct = 0; ct < 4; ++ct) {
            const int row = wc * 64 + ct * 16 + lr;
            const int sw  = (row & 7) << 4;
            const frag8 b0 = *(const frag8*)((const char*)Bs + row * 128 + ((lg * 16) ^ sw));
            const frag8 b1 = *(const frag8*)((const char*)Bs + row * 128 + ((64 + lg * 16) ^ sw));
#pragma unroll
            for (int rt = 0; rt < 4; ++rt) {
                acc[rt][ct] = __builtin_amdgcn_mfma_f32_16x16x32_bf16(af[rt][0], b0, acc[rt][ct], 0, 0, 0);
                acc[rt][ct] = __builtin_amdgcn_mfma_f32_16x16x32_bf16(af[rt][1], b1, acc[rt][ct], 0, 0, 0);
            }
        }
        __syncthreads();
    }

    // Epilogue: scatter to head-major q/k [bh][n][64]; fold scale=1/32 into q
    // (exact power of two -> no bf16 precision loss).
#pragma unroll
    for (int rt = 0; rt < 4; ++rt) {
#pragma unroll
        for (int ct = 0; ct < 4; ++ct) {
            const int eg = e0 + wc * 64 + ct * 16 + lr;
#pragma unroll
            for (int r = 0; r < 4; ++r) {
                const int   mg = m0 + wr * 64 + rt * 16 + lg * 4 + r;  // C/D: row=(lane>>4)*4+reg
                const int   b  = mg >> 11;
                const int   n  = mg & (N_ - 1);
                const float val = acc[rt][ct][r];
                if (eg < DIM_) {
                    const int h = eg >> 6, d = eg & 63;
                    qo[((size_t)((b * HEAD_ + h) * N_ + n)) * HD_ + d] = f2bf(val * 0.03125f);
                } else {
                    const int e2 = eg - DIM_;
                    const int h = e2 >> 6, d = e2 & 63;
                    ko[((size_t)((b * HEAD_ + h) * N_ + n)) * HD_ + d] = f2bf(val);
                }
            }
        }
    }
}

// ---------------- Kernel 3: attention with rank-1 V ----------------
// Block = one (b,h) x 128 q-rows. Stream 16 k-chunks of 128. Scores via
// 16x16x32 MFMA; exp without max-subtraction (|s| <~ 2 by construction);
// per-row num/den accumulated in registers, single 16-lane butterfly at end.
__global__ __launch_bounds__(256) void attn_kernel(const unsigned short* __restrict__ q,
                                                   const unsigned short* __restrict__ kmat,
                                                   const float* __restrict__ Ain,
                                                   const float* __restrict__ wv,
                                                   float* __restrict__ outp) {
    __shared__ __attribute__((aligned(16))) unsigned short Qs[128 * 64];
    __shared__ __attribute__((aligned(16))) unsigned short Ks[128 * 64];
    __shared__ float Vs[128];
    const int t    = threadIdx.x;
    const int lane = t & 63, w = t >> 6;        // 4 waves, 32 q-rows each
    const int lr   = lane & 15, lg = lane >> 4;
    const int bh   = blockIdx.x >> 4;           // 0..63
    const int nt   = blockIdx.x & 15;
    const int b    = bh >> 4, h = bh & 15;
    const float wvv = wv[0];

    const unsigned short* qbase = q    + ((size_t)bh * N_ + nt * 128) * HD_;
    const unsigned short* kbase = kmat +  (size_t)bh * N_ * HD_;

    // stage Q tile once (same both-sides swizzle as GEMM)
#pragma unroll
    for (int it = 0; it < 4; ++it) {
        const int seg = it * 256 + t;
        const int row = seg >> 3;
        const int ss  = (seg & 7) ^ (row & 7);
        gld_lds16(qbase + (size_t)row * HD_ + ss * 8,
                  (unsigned short*)Qs + (size_t)(it * 256 + (t & ~63)) * 8);
    }

    float num[2][4] = {}, den[2][4] = {};
    frag8 qf[2][2];

    for (int c = 0; c < 16; ++c) {
#pragma unroll
        for (int it = 0; it < 4; ++it) {
            const int seg = it * 256 + t;
            const int row = seg >> 3;
            const int ss  = (seg & 7) ^ (row & 7);
            gld_lds16(kbase + (size_t)(c * 128 + row) * HD_ + ss * 8,
                      (unsigned short*)Ks + (size_t)(it * 256 + (t & ~63)) * 8);
        }
        if (t < 128) Vs[t] = Ain[((size_t)(b * N_ + c * 128 + t)) * HEAD_ + h] * wvv;
        __syncthreads();

        if (c == 0) {
#pragma unroll
            for (int rt = 0; rt < 2; ++rt) {
                const int row = w * 32 + rt * 16 + lr;
                const int sw  = (row & 7) << 4;
                qf[rt][0] = *(const frag8*)((const char*)Qs + row * 128 + ((lg * 16) ^ sw));
                qf[rt][1] = *(const frag8*)((const char*)Qs + row * 128 + ((64 + lg * 16) ^ sw));
            }
        }

#pragma unroll
        for (int ct = 0; ct < 8; ++ct) {
            const int row = ct * 16 + lr;
            const int sw  = (row & 7) << 4;
            const frag8 k0 = *(const frag8*)((const char*)Ks + row * 128 + ((lg * 16) ^ sw));
            const frag8 k1 = *(const frag8*)((const char*)Ks + row * 128 + ((64 + lg * 16) ^ sw));
            const float vv = Vs[ct * 16 + lr];
#pragma unroll
            for (int rt = 0; rt < 2; ++rt) {
                facc4 s_ = {0.f, 0.f, 0.f, 0.f};
                s_ = __builtin_amdgcn_mfma_f32_16x16x32_bf16(qf[rt][0], k0, s_, 0, 0, 0);
                s_ = __builtin_amdgcn_mfma_f32_16x16x32_bf16(qf[rt][1], k1, s_, 0, 0, 0);
#pragma unroll
                for (int r = 0; r < 4; ++r) {
                    const float e = __expf(s_[r]);
                    den[rt][r] += e;
                    num[rt][r] += e * vv;
                }
            }
        }
        __syncthreads();
    }

    // final per-row reduction across the 16 column-lanes, then write
#pragma unroll
    for (int rt = 0; rt < 2; ++rt) {
#pragma unroll
        for (int r = 0; r < 4; ++r) {
            float nsum = num[rt][r], dsum = den[rt][r];
#pragma unroll
            for (int off = 1; off < 16; off <<= 1) {
                nsum += __shfl_xor(nsum, off);
                dsum += __shfl_xor(dsum, off);
            }
            if (lr == 0) {
                const int row = nt * 128 + w * 32 + rt * 16 + lg * 4 + r;
                const size_t gi = (size_t)(b * N_ + row) * HEAD_ + h;
                outp[gi] = Ain[gi] + nsum / dsum;
            }
        }
    }
}

// ---------------- launch ----------------
extern "C" void kernel_launch(void* const* d_in, const int* in_sizes, int n_in,
                              void* d_out, int out_size, void* d_ws, size_t ws_size,
                              hipStream_t stream) {
    const float* x   = (const float*)d_in[0];
    const float* A   = (const float*)d_in[1];
    const float* lw  = (const float*)d_in[2];
    const float* lb  = (const float*)d_in[3];
    const float* Wqk = (const float*)d_in[4];
    const float* wv  = (const float*)d_in[5];
    float* outp = (float*)d_out;

    char* ws = (char*)d_ws;
    unsigned short* xn = (unsigned short*)(ws);                      // 16 MB
    unsigned short* wb = (unsigned short*)(ws + 16u * 1024 * 1024);  //  4 MB
    unsigned short* qb = (unsigned short*)(ws + 20u * 1024 * 1024);  // 16 MB
    unsigned short* kb = (unsigned short*)(ws + 36u * 1024 * 1024);  // 16 MB

    ln_kernel<<<M_, 256, 0, stream>>>(x, lw, lb, xn);
    cvt_kernel<<<(E_ * DIM_ / 4) / 256, 256, 0, stream>>>(Wqk, wb);
    gemm_qk<<<64 * 16, 256, 0, stream>>>(xn, wb, qb, kb);
    attn_kernel<<<64 * 16, 256, 0, stream>>>(qb, kb, A, wv, outp);
}